// Round 8
// baseline (390.384 us; speedup 1.0000x reference)
//
#include <hip/hip_runtime.h>
#include <hip/hip_bf16.h>
#include <cstdint>
#include <cstddef>

typedef __bf16 bf16x8 __attribute__((ext_vector_type(8)));
typedef float f32x4 __attribute__((ext_vector_type(4)));

#define AS1(p) ((const __attribute__((address_space(1))) void*)(p))
#define AS3(p) ((__attribute__((address_space(3))) void*)(p))

__device__ __forceinline__ unsigned short f2bf_rne(float f) {
    union { float f; unsigned u; } c; c.f = f;
    unsigned u = c.u;
    unsigned r = (u + 0x7FFFu + ((u >> 16) & 1u)) >> 16;
    return (unsigned short)r;
}

// tanh-form GELU, NaN-free: g = v - v/(e^{2u}+1), 2u = v*(C1 + C2*v^2)
// max |diff vs exact erf-GELU| ~5e-4 (at |v|~2.5); stateless & deterministic.
__device__ __forceinline__ float gelu_fast(float v) {
    const float C1 = 1.5957691216057308f;    // 2*sqrt(2/pi)
    const float C2 = 0.07135481627247335f;   // 2*sqrt(2/pi)*0.044715
    float vv = v * v;
    float U = v * __builtin_fmaf(C2, vv, C1);      // 2u
    float t = __expf(U);                            // e^{2u}
    return v - v * __builtin_amdgcn_rcpf(t + 1.0f);
}

// -------- fused prologue: wave-granular, no shared mem, no syncthreads --------
// 1280 blocks x 4 waves = 5120 waves: wave gw<4096 binarizes w1 row gw (C=1024);
// gw in [4096,5120) binarizes w2 row gw-4096 (C=4096). Wave-local shuffle
// reduction only (branch is wave-uniform; no cross-wave state). Then ALL
// blocks grid-stride convert x -> bf16. Pure function of inputs on every call.
__global__ __launch_bounds__(256)
void prologue_k(const float* __restrict__ w1, unsigned short* __restrict__ s1, float* __restrict__ a1,
                const float* __restrict__ w2, unsigned short* __restrict__ s2, float* __restrict__ a2,
                const float* __restrict__ x, unsigned short* __restrict__ xb,
                int n4cvt, int totThreads) {
    const int wid  = threadIdx.x >> 6;
    const int lane = threadIdx.x & 63;
    const int gw   = blockIdx.x * 4 + wid;   // global wave id

    // ---- binarize one weight row per wave ----
    {
        const float* W; unsigned short* Sg; float* Al; int C, r;
        if (gw < 4096) { W = w1; Sg = s1; Al = a1; C = 1024; r = gw; }
        else           { W = w2; Sg = s2; Al = a2; C = 4096; r = gw - 4096; }
        const float4* w = (const float4*)(W + (size_t)r * C);
        ushort4* s = (ushort4*)(Sg + (size_t)r * C);
        const int n4 = C >> 2;
        float lsum = 0.f;
        for (int i = lane; i < n4; i += 64) {
            float4 v = w[i];
            lsum += fabsf(v.x) + fabsf(v.y) + fabsf(v.z) + fabsf(v.w);
            ushort4 o;
            o.x = (v.x == 0.f) ? 0 : ((v.x < 0.f) ? 0xBF80 : 0x3F80);
            o.y = (v.y == 0.f) ? 0 : ((v.y < 0.f) ? 0xBF80 : 0x3F80);
            o.z = (v.z == 0.f) ? 0 : ((v.z < 0.f) ? 0xBF80 : 0x3F80);
            o.w = (v.w == 0.f) ? 0 : ((v.w < 0.f) ? 0xBF80 : 0x3F80);
            s[i] = o;
        }
        for (int o = 32; o > 0; o >>= 1) lsum += __shfl_down(lsum, o, 64);
        if (lane == 0) Al[r] = lsum / (float)C;
    }

    // ---- convert x -> bf16 (grid-stride, all blocks) ----
    for (int i = blockIdx.x * 256 + threadIdx.x; i < n4cvt; i += totThreads) {
        float4 v = ((const float4*)x)[i];
        ushort4 o;
        o.x = f2bf_rne(v.x); o.y = f2bf_rne(v.y);
        o.z = f2bf_rne(v.z); o.w = f2bf_rne(v.w);
        ((ushort4*)xb)[i] = o;
    }
}

// -------- binary-weight GEMM, m97 structure + conflict-free xor swizzle (r7-exact) --------
// C[m,n] = act(alpha[n] * sum_k A[m,k]*S[n,k] + bias[n])
// A bf16 [M,K] row-major; S bf16 sign [N,K] row-major (B^T layout).
// BM=128, BN in {128,64}, BK=64, 256 thr = 4 waves (2x2).
// LDS [R][64] col-slot xor swizzle (slot ^ row&7): pre-swizzled global source,
// linear global_load_lds dest, same xor on read -> 0 bank conflicts.
template<int GELU, int BN>
__global__ __launch_bounds__(256)
void gemm_bin(const unsigned short* __restrict__ A,
              const unsigned short* __restrict__ S,
              const float* __restrict__ alpha,
              const float* __restrict__ bias,
              unsigned short* __restrict__ Obf,
              float* __restrict__ Of32,
              int M, int N, int K)
{
    constexpr int WN = BN / 2;
    constexpr int NFRAG = WN / 16;

    __shared__ __align__(16) unsigned short As[128 * 64];
    __shared__ __align__(16) unsigned short Ss[BN * 64];

    const int tid  = threadIdx.x;
    const int lane = tid & 63;
    const int wid  = tid >> 6;
    const int wr   = wid >> 1, wc = wid & 1;
    const int lr   = lane & 15;
    const int hi   = lane >> 4;
    const int xorv = lr & 7;

    // bijective XCD-aware block swizzle (m204 form)
    const int nbn = N / BN, nbm = M >> 7;
    const int nwg = nbm * nbn;
    const int q = nwg >> 3, r = nwg & 7;
    const int xcd = blockIdx.x & 7, loc = blockIdx.x >> 3;
    const int swz = (xcd < r ? xcd * (q + 1) : r * (q + 1) + (xcd - r) * q) + loc;
    const int bm = swz / nbn, bn = swz % nbn;

    const unsigned short* gA = A + (size_t)bm * 128 * K;
    const unsigned short* gS = S + (size_t)bn * BN * K;

    f32x4 acc[4][NFRAG] = {};

    const int nkt = K >> 6;
    for (int kt = 0; kt < nkt; ++kt) {
        const int k0 = kt << 6;
#pragma unroll
        for (int j = 0; j < 4; ++j) {
            const int u = j * 256 + tid;
            const int row = u >> 3;
            const int sc = ((u & 7) ^ (row & 7)) << 3;
            __builtin_amdgcn_global_load_lds(AS1(gA + (size_t)row * K + k0 + sc),
                                             AS3(&As[0] + u * 8), 16, 0, 0);
        }
#pragma unroll
        for (int j = 0; j < BN / 32; ++j) {
            const int u = j * 256 + tid;
            const int row = u >> 3;
            const int sc = ((u & 7) ^ (row & 7)) << 3;
            __builtin_amdgcn_global_load_lds(AS1(gS + (size_t)row * K + k0 + sc),
                                             AS3(&Ss[0] + u * 8), 16, 0, 0);
        }
        __syncthreads();

        bf16x8 af[2][4], bf[2][NFRAG];
#pragma unroll
        for (int ks = 0; ks < 2; ++ks) {
            const int kg = ((ks << 2) + hi) ^ xorv;
#pragma unroll
            for (int mf = 0; mf < 4; ++mf)
                af[ks][mf] = *(const bf16x8*)(&As[0] + (wr * 64 + mf * 16 + lr) * 64 + kg * 8);
#pragma unroll
            for (int nf = 0; nf < NFRAG; ++nf)
                bf[ks][nf] = *(const bf16x8*)(&Ss[0] + (wc * WN + nf * 16 + lr) * 64 + kg * 8);
        }
#pragma unroll
        for (int ks = 0; ks < 2; ++ks)
#pragma unroll
            for (int mf = 0; mf < 4; ++mf)
#pragma unroll
                for (int nf = 0; nf < NFRAG; ++nf)
                    acc[mf][nf] = __builtin_amdgcn_mfma_f32_16x16x32_bf16(
                        af[ks][mf], bf[ks][nf], acc[mf][nf], 0, 0, 0);
        __syncthreads();
    }

    // epilogue: alpha*acc + bias, optional fast GELU, store
    const int col0 = bn * BN + wc * WN;
    const int row0 = bm * 128 + wr * 64;
    float al[NFRAG], bi[NFRAG];
#pragma unroll
    for (int nf = 0; nf < NFRAG; ++nf) {
        const int n = col0 + nf * 16 + lr;
        al[nf] = alpha[n];
        bi[nf] = bias[n];
    }
#pragma unroll
    for (int mf = 0; mf < 4; ++mf) {
#pragma unroll
        for (int j = 0; j < 4; ++j) {
            const int m = row0 + mf * 16 + hi * 4 + j;
#pragma unroll
            for (int nf = 0; nf < NFRAG; ++nf) {
                const int n = col0 + nf * 16 + lr;
                float v = acc[mf][nf][j] * al[nf] + bi[nf];
                if (GELU) {
                    Obf[(size_t)m * N + n] = f2bf_rne(gelu_fast(v));
                } else {
                    Of32[(size_t)m * N + n] = v;
                }
            }
        }
    }
}

extern "C" void kernel_launch(void* const* d_in, const int* in_sizes, int n_in,
                              void* d_out, int out_size, void* d_ws, size_t ws_size,
                              hipStream_t stream) {
    const float* x  = (const float*)d_in[0];
    const float* w1 = (const float*)d_in[1];
    const float* b1 = (const float*)d_in[2];
    const float* w2 = (const float*)d_in[3];
    const float* b2 = (const float*)d_in[4];
    float* out = (float*)d_out;

    const int D = 1024, H = 4096;
    const int M = in_sizes[0] / D;   // 12544

    char* ws = (char*)d_ws;
    size_t off = 0;
    auto alloc = [&](size_t bytes) -> void* {
        void* p = ws + off;
        off = (off + bytes + 255) & ~(size_t)255;
        return p;
    };
    unsigned short* xb = (unsigned short*)alloc((size_t)M * D * 2);
    unsigned short* s1 = (unsigned short*)alloc((size_t)H * D * 2);
    float*          a1 = (float*)alloc((size_t)H * 4);
    unsigned short* s2 = (unsigned short*)alloc((size_t)D * H * 2);
    float*          a2 = (float*)alloc((size_t)D * 4);
    unsigned short* hb = (unsigned short*)alloc((size_t)M * H * 2);

    // fused prologue: (H+D)/4 = 1280 blocks; 5120 waves cover all weight rows,
    // then all blocks grid-stride convert x.
    const int NB = (H + D) / 4;
    const int n4cvt = (M * D) / 4;
    prologue_k<<<NB, 256, 0, stream>>>(w1, s1, a1, w2, s2, a2, x, xb, n4cvt, NB * 256);

    gemm_bin<1, 128><<<(M / 128) * (H / 128), 256, 0, stream>>>(xb, s1, a1, b1, hb, nullptr, M, H, D);
    gemm_bin<0, 64><<<(M / 128) * (D / 64), 256, 0, stream>>>(hb, s2, a2, b2, nullptr, out, M, D, H);
}